// Round 1
// baseline (1773.994 us; speedup 1.0000x reference)
//
#include <hip/hip_runtime.h>
#include <stdint.h>

#define B_N 64
#define I_N 2048
#define DIN 16
#define J_N 32
#define D_N 32

// ws layout:
//   uhat bf16 [b][i][j][d]: 64*2048*32*32 = 134217728 bf16 = 268435456 bytes (as uint32 words)
//   s    fp32 [b][j][d]   : 65536 floats
//   acc  fp32 [b][j][d]   : 65536 floats
#define UH_BYTES 268435456ULL

__device__ __forceinline__ uint32_t pk_bf16(float a, float b) {
  uint32_t ua = __float_as_uint(a), ub = __float_as_uint(b);
  uint32_t ra = (ua + 0x7fffu + ((ua >> 16) & 1u)) >> 16;
  uint32_t rb = (ub + 0x7fffu + ((ub >> 16) & 1u)) & 0xffff0000u;
  return (ra & 0xffffu) | rb;
}

__global__ void k_zero(float* __restrict__ p) {
  int t = blockIdx.x * 256 + threadIdx.x;   // 32768 float4 = 131072 floats
  ((float4*)p)[t] = float4{0.f, 0.f, 0.f, 0.f};
}

// ---------------- K1: build u_hat (bf16) ----------------
// grid 256 blocks (i-chunks of 8), 512 threads: thread = (bq in 0..15 -> 4 b's, j in 0..31)
// W[j,i,:,:] (64KB per i) staged to LDS (pad 514 -> conflict-free b64 reads), reg-staged
// double-pipeline with raw barriers so next-i global loads overlap compute.
__global__ __launch_bounds__(512) void k_uhat(const float* __restrict__ xg,
                                              const float* __restrict__ Wg,
                                              uint32_t* __restrict__ uh) {
  __shared__ float Wl[32 * 514];
  const int tid = threadIdx.x;
  const int j = tid & 31;
  const int b0 = (tid >> 5) << 2;
  const int i0 = blockIdx.x * 8;

  float4 st[8];
#pragma unroll
  for (int k = 0; k < 8; ++k) {          // prologue load, i = i0
    int g = tid + k * 512;
    int jj = g >> 7, u = g & 127;
    st[k] = *(const float4*)(Wg + ((size_t)jj * I_N + i0) * 512 + u * 4);
  }

#pragma unroll 1
  for (int il = 0; il < 8; ++il) {
    const int i = i0 + il;
    asm volatile("s_waitcnt lgkmcnt(0)" ::: "memory");
    __builtin_amdgcn_s_barrier();        // everyone done reading Wl from prev iter
#pragma unroll
    for (int k = 0; k < 8; ++k) {        // regs -> LDS (8B-granule, pad keeps banks spread)
      int g = tid + k * 512;
      int jj = g >> 7, u = g & 127;
      float* dst = &Wl[jj * 514 + u * 4];
      *(float2*)dst = float2{st[k].x, st[k].y};
      *(float2*)(dst + 2) = float2{st[k].z, st[k].w};
    }
    if (il < 7) {                        // issue next-i loads; hidden under compute
      const int inx = i + 1;
#pragma unroll
      for (int k = 0; k < 8; ++k) {
        int g = tid + k * 512;
        int jj = g >> 7, u = g & 127;
        st[k] = *(const float4*)(Wg + ((size_t)jj * I_N + inx) * 512 + u * 4);
      }
    }
    asm volatile("s_waitcnt lgkmcnt(0)" ::: "memory");
    __builtin_amdgcn_s_barrier();        // staged slice visible

    float xf[4][16];
#pragma unroll
    for (int kb = 0; kb < 4; ++kb)
#pragma unroll
      for (int kc = 0; kc < 4; ++kc)
        *(float4*)&xf[kb][kc * 4] =
            *(const float4*)(xg + ((size_t)(b0 + kb) * I_N + i) * DIN + kc * 4);

    const float* wj = &Wl[j * 514];
#pragma unroll
    for (int dpg = 0; dpg < 4; ++dpg) {
      uint32_t pk[4][4];
#pragma unroll
      for (int dq = 0; dq < 4; ++dq) {
        const int dp = dpg * 4 + dq;     // d pair (2dp, 2dp+1)
        float2 w0[8], w1[8];
#pragma unroll
        for (int kc = 0; kc < 8; ++kc) {
          w0[kc] = *(const float2*)(wj + dp * 32 + kc * 2);
          w1[kc] = *(const float2*)(wj + dp * 32 + 16 + kc * 2);
        }
#pragma unroll
        for (int kb = 0; kb < 4; ++kb) {
          float a0 = 0.f, a1 = 0.f;
#pragma unroll
          for (int kc = 0; kc < 8; ++kc) {
            a0 = fmaf(w0[kc].x, xf[kb][2 * kc], a0);
            a0 = fmaf(w0[kc].y, xf[kb][2 * kc + 1], a0);
            a1 = fmaf(w1[kc].x, xf[kb][2 * kc], a1);
            a1 = fmaf(w1[kc].y, xf[kb][2 * kc + 1], a1);
          }
          pk[kb][dq] = pk_bf16(a0, a1);
        }
      }
#pragma unroll
      for (int kb = 0; kb < 4; ++kb) {
        uint32_t* dst =
            uh + (((size_t)(b0 + kb) * I_N + i) * J_N + j) * 16 + dpg * 4;
        *(uint4*)dst = uint4{pk[kb][0], pk[kb][1], pk[kb][2], pk[kb][3]};
      }
    }
  }
}

// ---------------- P: one routing sweep ----------------
// logits b_t[b,j,i] == acc_out[b,j,:] . u_hat[b,i,j,:]  (acc_out = sum of prior outputs).
// grid 1024 = (b 64) x (ic 16); 512 threads = 8 waves; lane = (j, ih); wave covers 16 i.
__global__ __launch_bounds__(512) void k_route(const uint32_t* __restrict__ uh,
                                               const float* __restrict__ accg,
                                               float* __restrict__ sg) {
  const int b = blockIdx.x >> 4;
  const int ic = blockIdx.x & 15;
  const int tid = threadIdx.x;
  const int wave = tid >> 6;
  const int lane = tid & 63;
  const int j = lane & 31;
  const int ih = lane >> 5;

  float a[32];
  {
    const float* ap = accg + ((size_t)b * J_N + j) * D_N;
#pragma unroll
    for (int k = 0; k < 8; ++k) *(float4*)&a[k * 4] = *(const float4*)(ap + k * 4);
  }
  float sp[32];
#pragma unroll
  for (int d = 0; d < 32; ++d) sp[d] = 0.f;

  const int ibase = ic * 128 + wave * 16;
#pragma unroll 1
  for (int t = 0; t < 8; ++t) {
    const int i = ibase + t * 2 + ih;
    const uint4* up = (const uint4*)(uh + (((size_t)b * I_N + i) * J_N + j) * 16);
    uint4 q0 = up[0], q1 = up[1], q2 = up[2], q3 = up[3];
    uint32_t u[16] = {q0.x, q0.y, q0.z, q0.w, q1.x, q1.y, q1.z, q1.w,
                      q2.x, q2.y, q2.z, q2.w, q3.x, q3.y, q3.z, q3.w};
    float logit = 0.f;
#pragma unroll
    for (int k = 0; k < 16; ++k) {
      float lo = __uint_as_float(u[k] << 16);
      float hi = __uint_as_float(u[k] & 0xffff0000u);
      logit = fmaf(a[2 * k], lo, logit);
      logit = fmaf(a[2 * k + 1], hi, logit);
    }
    // softmax over j = 32-lane group reduce (xor masks <32 stay in-group)
    float m = logit;
#pragma unroll
    for (int off = 16; off >= 1; off >>= 1) m = fmaxf(m, __shfl_xor(m, off));
    float e = __expf(logit - m);
    float den = e;
#pragma unroll
    for (int off = 16; off >= 1; off >>= 1) den += __shfl_xor(den, off);
    float c = e / den;
#pragma unroll
    for (int k = 0; k < 16; ++k) {
      float lo = __uint_as_float(u[k] << 16);
      float hi = __uint_as_float(u[k] & 0xffff0000u);
      sp[2 * k] = fmaf(c, lo, sp[2 * k]);
      sp[2 * k + 1] = fmaf(c, hi, sp[2 * k + 1]);
    }
  }
#pragma unroll
  for (int d = 0; d < 32; ++d) sp[d] += __shfl_xor(sp[d], 32);  // fold the 2 i's
  if (ih == 0) {
    float* sd = sg + ((size_t)b * J_N + j) * D_N;
#pragma unroll
    for (int d = 0; d < 32; ++d) atomicAdd(sd + d, sp[d]);
  }
}

// ---------------- Q: squash + acc update / final write ----------------
template <int FINAL>
__global__ void k_squash(float* __restrict__ sg, float* __restrict__ accg,
                         float* __restrict__ outg) {
  const int t = blockIdx.x * 256 + threadIdx.x;  // 0..2047 = (b*32 + j)
  float v[32];
  float* sd = sg + (size_t)t * 32;
#pragma unroll
  for (int k = 0; k < 8; ++k) *(float4*)&v[k * 4] = *(const float4*)(sd + k * 4);
  float s2 = 0.f;
#pragma unroll
  for (int d = 0; d < 32; ++d) s2 = fmaf(v[d], v[d], s2);
  const float scale = s2 / ((1.f + s2) * sqrtf(s2 + 1e-7f));
  if (FINAL) {
    float* od = outg + (size_t)t * 32;
#pragma unroll
    for (int k = 0; k < 8; ++k) {
      float4 o{scale * v[k * 4], scale * v[k * 4 + 1], scale * v[k * 4 + 2],
               scale * v[k * 4 + 3]};
      *(float4*)(od + k * 4) = o;
    }
  } else {
    float* ad = accg + (size_t)t * 32;
#pragma unroll
    for (int k = 0; k < 8; ++k) {
      float4 av = *(const float4*)(ad + k * 4);
      av.x += scale * v[k * 4];
      av.y += scale * v[k * 4 + 1];
      av.z += scale * v[k * 4 + 2];
      av.w += scale * v[k * 4 + 3];
      *(float4*)(ad + k * 4) = av;
      *(float4*)(sd + k * 4) = float4{0.f, 0.f, 0.f, 0.f};  // reset for next pass
    }
  }
}

extern "C" void kernel_launch(void* const* d_in, const int* in_sizes, int n_in,
                              void* d_out, int out_size, void* d_ws, size_t ws_size,
                              hipStream_t stream) {
  const float* x = (const float*)d_in[0];   // [64,2048,16]
  const float* W = (const float*)d_in[1];   // [32,2048,32,16]
  float* out = (float*)d_out;               // [64,32,32]
  uint32_t* uh = (uint32_t*)d_ws;
  float* s = (float*)((char*)d_ws + (size_t)UH_BYTES);
  float* acc = s + 65536;

  k_zero<<<128, 256, 0, stream>>>(s);                 // zeros s and acc (contiguous)
  k_uhat<<<256, 512, 0, stream>>>(x, W, uh);
  k_route<<<1024, 512, 0, stream>>>(uh, acc, s);      // iter 0 (acc=0 -> uniform c)
  k_squash<0><<<8, 256, 0, stream>>>(s, acc, out);
  k_route<<<1024, 512, 0, stream>>>(uh, acc, s);      // iter 1
  k_squash<0><<<8, 256, 0, stream>>>(s, acc, out);
  k_route<<<1024, 512, 0, stream>>>(uh, acc, s);      // iter 2
  k_squash<1><<<8, 256, 0, stream>>>(s, acc, out);    // final squash -> d_out
}

// Round 2
// 801.854 us; speedup vs baseline: 2.2124x; 2.2124x over previous
//
#include <hip/hip_runtime.h>
#include <stdint.h>

#define B_N 64
#define I_N 2048
#define DIN 16
#define J_N 32
#define D_N 32

// ws layout:
//   uhat bf16 [b][i][j][d]: 268435456 bytes (uint32 words)
//   part fp32 [ic=16][b][j][d]: 16*64*32*32 = 1048576 floats = 4 MB
//   acc  fp32 [b][j][d]: 65536 floats = 256 KB
#define UH_BYTES 268435456ULL

__device__ __forceinline__ uint32_t pk_bf16(float a, float b) {
  uint32_t ua = __float_as_uint(a), ub = __float_as_uint(b);
  uint32_t ra = (ua + 0x7fffu + ((ua >> 16) & 1u)) >> 16;
  uint32_t rb = (ub + 0x7fffu + ((ub >> 16) & 1u)) & 0xffff0000u;
  return (ra & 0xffffu) | rb;
}

// ---------------- K1: build u_hat (bf16) ---------------- (unchanged)
__global__ __launch_bounds__(512) void k_uhat(const float* __restrict__ xg,
                                              const float* __restrict__ Wg,
                                              uint32_t* __restrict__ uh) {
  __shared__ float Wl[32 * 514];
  const int tid = threadIdx.x;
  const int j = tid & 31;
  const int b0 = (tid >> 5) << 2;
  const int i0 = blockIdx.x * 8;

  float4 st[8];
#pragma unroll
  for (int k = 0; k < 8; ++k) {
    int g = tid + k * 512;
    int jj = g >> 7, u = g & 127;
    st[k] = *(const float4*)(Wg + ((size_t)jj * I_N + i0) * 512 + u * 4);
  }

#pragma unroll 1
  for (int il = 0; il < 8; ++il) {
    const int i = i0 + il;
    asm volatile("s_waitcnt lgkmcnt(0)" ::: "memory");
    __builtin_amdgcn_s_barrier();
#pragma unroll
    for (int k = 0; k < 8; ++k) {
      int g = tid + k * 512;
      int jj = g >> 7, u = g & 127;
      float* dst = &Wl[jj * 514 + u * 4];
      *(float2*)dst = float2{st[k].x, st[k].y};
      *(float2*)(dst + 2) = float2{st[k].z, st[k].w};
    }
    if (il < 7) {
      const int inx = i + 1;
#pragma unroll
      for (int k = 0; k < 8; ++k) {
        int g = tid + k * 512;
        int jj = g >> 7, u = g & 127;
        st[k] = *(const float4*)(Wg + ((size_t)jj * I_N + inx) * 512 + u * 4);
      }
    }
    asm volatile("s_waitcnt lgkmcnt(0)" ::: "memory");
    __builtin_amdgcn_s_barrier();

    float xf[4][16];
#pragma unroll
    for (int kb = 0; kb < 4; ++kb)
#pragma unroll
      for (int kc = 0; kc < 4; ++kc)
        *(float4*)&xf[kb][kc * 4] =
            *(const float4*)(xg + ((size_t)(b0 + kb) * I_N + i) * DIN + kc * 4);

    const float* wj = &Wl[j * 514];
#pragma unroll
    for (int dpg = 0; dpg < 4; ++dpg) {
      uint32_t pk[4][4];
#pragma unroll
      for (int dq = 0; dq < 4; ++dq) {
        const int dp = dpg * 4 + dq;
        float2 w0[8], w1[8];
#pragma unroll
        for (int kc = 0; kc < 8; ++kc) {
          w0[kc] = *(const float2*)(wj + dp * 32 + kc * 2);
          w1[kc] = *(const float2*)(wj + dp * 32 + 16 + kc * 2);
        }
#pragma unroll
        for (int kb = 0; kb < 4; ++kb) {
          float a0 = 0.f, a1 = 0.f;
#pragma unroll
          for (int kc = 0; kc < 8; ++kc) {
            a0 = fmaf(w0[kc].x, xf[kb][2 * kc], a0);
            a0 = fmaf(w0[kc].y, xf[kb][2 * kc + 1], a0);
            a1 = fmaf(w1[kc].x, xf[kb][2 * kc], a1);
            a1 = fmaf(w1[kc].y, xf[kb][2 * kc + 1], a1);
          }
          pk[kb][dq] = pk_bf16(a0, a1);
        }
      }
#pragma unroll
      for (int kb = 0; kb < 4; ++kb) {
        uint32_t* dst =
            uh + (((size_t)(b0 + kb) * I_N + i) * J_N + j) * 16 + dpg * 4;
        *(uint4*)dst = uint4{pk[kb][0], pk[kb][1], pk[kb][2], pk[kb][3]};
      }
    }
  }
}

// ---------------- P: one routing sweep (no atomics) ----------------
// grid (b=64) x (ic=16); 512 thr = 8 waves. lane = (j in 0..31, ih = d-half).
// Each wave covers 16 i (one i per t-iter, whole 2KB row coalesced across 64 lanes).
// Block partial -> LDS cross-wave reduce -> plain store to part[ic][b][j][d].
template <int FIRST>
__global__ __launch_bounds__(512) void k_route(const uint32_t* __restrict__ uh,
                                               const float* __restrict__ accg,
                                               float* __restrict__ part) {
  const int b = blockIdx.x >> 4;
  const int ic = blockIdx.x & 15;
  const int tid = threadIdx.x;
  const int wv = tid >> 6;
  const int lane = tid & 63;
  const int j = lane & 31;
  const int ih = lane >> 5;

  float a[16];
  if (!FIRST) {
    const float* ap = accg + ((size_t)b * J_N + j) * D_N + ih * 16;
#pragma unroll
    for (int k = 0; k < 4; ++k) *(float4*)&a[k * 4] = *(const float4*)(ap + k * 4);
  }
  float sp[16];
#pragma unroll
  for (int d = 0; d < 16; ++d) sp[d] = 0.f;

  const int i0 = ic * 128 + wv * 16;
  const uint32_t* up = uh + ((size_t)b * I_N + i0) * 512 + j * 16 + ih * 8;

  uint4 q[2][2];
  q[0][0] = *(const uint4*)(up);
  q[0][1] = *(const uint4*)(up + 4);

#pragma unroll
  for (int t = 0; t < 16; ++t) {
    const int cur = t & 1;
    if (t < 15) {
      const uint32_t* np = up + (size_t)(t + 1) * 512;
      q[cur ^ 1][0] = *(const uint4*)(np);
      q[cur ^ 1][1] = *(const uint4*)(np + 4);
    }
    const uint32_t u[8] = {q[cur][0].x, q[cur][0].y, q[cur][0].z, q[cur][0].w,
                           q[cur][1].x, q[cur][1].y, q[cur][1].z, q[cur][1].w};
    float f[16];
#pragma unroll
    for (int k = 0; k < 8; ++k) {
      f[2 * k] = __uint_as_float(u[k] << 16);
      f[2 * k + 1] = __uint_as_float(u[k] & 0xffff0000u);
    }
    float c;
    if (FIRST) {
      c = 1.f / 32.f;
    } else {
      float lp = 0.f;
#pragma unroll
      for (int k = 0; k < 16; ++k) lp = fmaf(a[k], f[k], lp);
      const float logit = lp + __shfl_xor(lp, 32);  // combine d-halves
      float m = logit;
#pragma unroll
      for (int off = 16; off >= 1; off >>= 1) m = fmaxf(m, __shfl_xor(m, off));
      const float e = __expf(logit - m);
      float den = e;
#pragma unroll
      for (int off = 16; off >= 1; off >>= 1) den += __shfl_xor(den, off);
      c = e / den;
    }
#pragma unroll
    for (int k = 0; k < 16; ++k) sp[k] = fmaf(c, f[k], sp[k]);
  }

  __shared__ float red[8][32][33];
  {
    float* rp = &red[wv][j][ih * 16];
#pragma unroll
    for (int k = 0; k < 4; ++k) *(float4*)(rp + k * 4) = *(float4*)&sp[k * 4];
  }
  __syncthreads();
  const int o = tid * 2;  // 0..1022: (j = o>>5, d = o&31)
  const int jj = o >> 5;
  const int dd = o & 31;
  float2 v{0.f, 0.f};
#pragma unroll
  for (int w = 0; w < 8; ++w) {
    v.x += red[w][jj][dd];
    v.y += red[w][jj][dd + 1];
  }
  *(float2*)(part + ((size_t)ic * 64 + b) * 1024 + o) = v;
}

// ---------------- Q: fold 16 partials + squash ----------------
// MODE 0: acc = squash(s); MODE 1: acc += squash(s); MODE 2: out = squash(s)
template <int MODE>
__global__ void k_squash(const float* __restrict__ part, float* __restrict__ accg,
                         float* __restrict__ outg) {
  const int t = blockIdx.x * 256 + threadIdx.x;  // 0..2047 = b*32+j
  float v[32];
#pragma unroll
  for (int d = 0; d < 32; ++d) v[d] = 0.f;
#pragma unroll 1
  for (int ic = 0; ic < 16; ++ic) {
    const float* p = part + ((size_t)ic * 2048 + t) * 32;
#pragma unroll
    for (int k = 0; k < 8; ++k) {
      float4 q = *(const float4*)(p + k * 4);
      v[k * 4] += q.x;
      v[k * 4 + 1] += q.y;
      v[k * 4 + 2] += q.z;
      v[k * 4 + 3] += q.w;
    }
  }
  float s2 = 0.f;
#pragma unroll
  for (int d = 0; d < 32; ++d) s2 = fmaf(v[d], v[d], s2);
  const float scale = s2 / ((1.f + s2) * sqrtf(s2 + 1e-7f));
  float* dp = ((MODE == 2) ? outg : accg) + (size_t)t * 32;
  if (MODE == 1) {
#pragma unroll
    for (int k = 0; k < 8; ++k) {
      float4 av = *(const float4*)(dp + k * 4);
      av.x += scale * v[k * 4];
      av.y += scale * v[k * 4 + 1];
      av.z += scale * v[k * 4 + 2];
      av.w += scale * v[k * 4 + 3];
      *(float4*)(dp + k * 4) = av;
    }
  } else {
#pragma unroll
    for (int k = 0; k < 8; ++k) {
      float4 o{scale * v[k * 4], scale * v[k * 4 + 1], scale * v[k * 4 + 2],
               scale * v[k * 4 + 3]};
      *(float4*)(dp + k * 4) = o;
    }
  }
}

extern "C" void kernel_launch(void* const* d_in, const int* in_sizes, int n_in,
                              void* d_out, int out_size, void* d_ws, size_t ws_size,
                              hipStream_t stream) {
  const float* x = (const float*)d_in[0];  // [64,2048,16]
  const float* W = (const float*)d_in[1];  // [32,2048,32,16]
  float* out = (float*)d_out;              // [64,32,32]
  uint32_t* uh = (uint32_t*)d_ws;
  float* part = (float*)((char*)d_ws + (size_t)UH_BYTES);
  float* acc = part + 16 * 64 * 1024;

  k_uhat<<<256, 512, 0, stream>>>(x, W, uh);
  k_route<1><<<1024, 512, 0, stream>>>(uh, acc, part);  // iter 0: uniform c
  k_squash<0><<<8, 256, 0, stream>>>(part, acc, out);   // acc = out0
  k_route<0><<<1024, 512, 0, stream>>>(uh, acc, part);  // iter 1
  k_squash<1><<<8, 256, 0, stream>>>(part, acc, out);   // acc = out0+out1
  k_route<0><<<1024, 512, 0, stream>>>(uh, acc, part);  // iter 2
  k_squash<2><<<8, 256, 0, stream>>>(part, acc, out);   // final -> d_out
}

// Round 3
// 507.374 us; speedup vs baseline: 3.4964x; 1.5804x over previous
//
#include <hip/hip_runtime.h>
#include <stdint.h>

#define B_N 64
#define I_N 2048
#define DIN 16
#define J_N 32
#define D_N 32

// ws layout:
//   uhat bf16 [b][i][dpg=4][j=32][dq=4 words]: 268435456 bytes
//     (word offset within a (b,i) row: dpg*128 + j*4 + dq; the bf16 pair in
//      word (dpg,j,dq) is d = {2*(dpg*4+dq), 2*(dpg*4+dq)+1} of capsule j)
//   part fp32 [ic=16][b][j][d]: 1048576 floats = 4 MB
//   acc  fp32 [b][j][d]: 65536 floats
#define UH_BYTES 268435456ULL

__device__ __forceinline__ uint32_t pk_bf16(float a, float b) {
  uint32_t ua = __float_as_uint(a), ub = __float_as_uint(b);
  uint32_t ra = (ua + 0x7fffu + ((ua >> 16) & 1u)) >> 16;
  uint32_t rb = (ub + 0x7fffu + ((ub >> 16) & 1u)) & 0xffff0000u;
  return (ra & 0xffffu) | rb;
}

// ---------------- K1: build u_hat (bf16) ----------------
// grid 512 blocks (i-chunks of 4 -> 2 blocks/CU), 512 threads.
// Stores now coalesced per instruction: lanes (j) write consecutive 16B.
__global__ __launch_bounds__(512) void k_uhat(const float* __restrict__ xg,
                                              const float* __restrict__ Wg,
                                              uint32_t* __restrict__ uh) {
  __shared__ float Wl[32 * 514];
  const int tid = threadIdx.x;
  const int j = tid & 31;
  const int b0 = (tid >> 5) << 2;
  const int i0 = blockIdx.x * 4;

  float4 st[8];
#pragma unroll
  for (int k = 0; k < 8; ++k) {
    int g = tid + k * 512;
    int jj = g >> 7, u = g & 127;
    st[k] = *(const float4*)(Wg + ((size_t)jj * I_N + i0) * 512 + u * 4);
  }

#pragma unroll 1
  for (int il = 0; il < 4; ++il) {
    const int i = i0 + il;
    asm volatile("s_waitcnt lgkmcnt(0)" ::: "memory");
    __builtin_amdgcn_s_barrier();
#pragma unroll
    for (int k = 0; k < 8; ++k) {
      int g = tid + k * 512;
      int jj = g >> 7, u = g & 127;
      float* dst = &Wl[jj * 514 + u * 4];
      *(float2*)dst = float2{st[k].x, st[k].y};
      *(float2*)(dst + 2) = float2{st[k].z, st[k].w};
    }
    if (il < 3) {
      const int inx = i + 1;
#pragma unroll
      for (int k = 0; k < 8; ++k) {
        int g = tid + k * 512;
        int jj = g >> 7, u = g & 127;
        st[k] = *(const float4*)(Wg + ((size_t)jj * I_N + inx) * 512 + u * 4);
      }
    }
    asm volatile("s_waitcnt lgkmcnt(0)" ::: "memory");
    __builtin_amdgcn_s_barrier();

    float xf[4][16];
#pragma unroll
    for (int kb = 0; kb < 4; ++kb)
#pragma unroll
      for (int kc = 0; kc < 4; ++kc)
        *(float4*)&xf[kb][kc * 4] =
            *(const float4*)(xg + ((size_t)(b0 + kb) * I_N + i) * DIN + kc * 4);

    const float* wj = &Wl[j * 514];
#pragma unroll
    for (int dpg = 0; dpg < 4; ++dpg) {
      uint32_t pk[4][4];
#pragma unroll
      for (int dq = 0; dq < 4; ++dq) {
        const int dp = dpg * 4 + dq;
        float2 w0[8], w1[8];
#pragma unroll
        for (int kc = 0; kc < 8; ++kc) {
          w0[kc] = *(const float2*)(wj + dp * 32 + kc * 2);
          w1[kc] = *(const float2*)(wj + dp * 32 + 16 + kc * 2);
        }
#pragma unroll
        for (int kb = 0; kb < 4; ++kb) {
          float a0 = 0.f, a1 = 0.f;
#pragma unroll
          for (int kc = 0; kc < 8; ++kc) {
            a0 = fmaf(w0[kc].x, xf[kb][2 * kc], a0);
            a0 = fmaf(w0[kc].y, xf[kb][2 * kc + 1], a0);
            a1 = fmaf(w1[kc].x, xf[kb][2 * kc], a1);
            a1 = fmaf(w1[kc].y, xf[kb][2 * kc + 1], a1);
          }
          pk[kb][dq] = pk_bf16(a0, a1);
        }
      }
#pragma unroll
      for (int kb = 0; kb < 4; ++kb) {
        // [b][i][dpg][j][dq]: lanes (j) -> consecutive 16B, coalesced store
        uint32_t* dst =
            uh + ((size_t)(b0 + kb) * I_N + i) * 512 + dpg * 128 + j * 4;
        *(uint4*)dst = uint4{pk[kb][0], pk[kb][1], pk[kb][2], pk[kb][3]};
      }
    }
  }
}

// ---------------- P: one routing sweep (no atomics) ----------------
// grid (b=64) x (ic=16); 512 thr = 8 waves. lane = (j, ih = d-half).
// Lane's 8 words: dpg = 2ih, 2ih+1 -> dp = 8ih+k, same d-order as before.
template <int FIRST>
__global__ __launch_bounds__(512) void k_route(const uint32_t* __restrict__ uh,
                                               const float* __restrict__ accg,
                                               float* __restrict__ part) {
  const int b = blockIdx.x >> 4;
  const int ic = blockIdx.x & 15;
  const int tid = threadIdx.x;
  const int wv = tid >> 6;
  const int lane = tid & 63;
  const int j = lane & 31;
  const int ih = lane >> 5;

  float a[16];
  if (!FIRST) {
    const float* ap = accg + ((size_t)b * J_N + j) * D_N + ih * 16;
#pragma unroll
    for (int k = 0; k < 4; ++k) *(float4*)&a[k * 4] = *(const float4*)(ap + k * 4);
  }
  float sp[16];
#pragma unroll
  for (int d = 0; d < 16; ++d) sp[d] = 0.f;

  const int i0 = ic * 128 + wv * 16;
  const uint32_t* up = uh + ((size_t)b * I_N + i0) * 512 + ih * 256 + j * 4;

  uint4 q[2][2];
  q[0][0] = *(const uint4*)(up);
  q[0][1] = *(const uint4*)(up + 128);

#pragma unroll
  for (int t = 0; t < 16; ++t) {
    const int cur = t & 1;
    if (t < 15) {
      const uint32_t* np = up + (size_t)(t + 1) * 512;
      q[cur ^ 1][0] = *(const uint4*)(np);
      q[cur ^ 1][1] = *(const uint4*)(np + 128);
    }
    const uint32_t u[8] = {q[cur][0].x, q[cur][0].y, q[cur][0].z, q[cur][0].w,
                           q[cur][1].x, q[cur][1].y, q[cur][1].z, q[cur][1].w};
    float f[16];
#pragma unroll
    for (int k = 0; k < 8; ++k) {
      f[2 * k] = __uint_as_float(u[k] << 16);
      f[2 * k + 1] = __uint_as_float(u[k] & 0xffff0000u);
    }
    float c;
    if (FIRST) {
      c = 1.f / 32.f;
    } else {
      float lp = 0.f;
#pragma unroll
      for (int k = 0; k < 16; ++k) lp = fmaf(a[k], f[k], lp);
      const float logit = lp + __shfl_xor(lp, 32);  // combine d-halves
      float m = logit;
#pragma unroll
      for (int off = 16; off >= 1; off >>= 1) m = fmaxf(m, __shfl_xor(m, off));
      const float e = __expf(logit - m);
      float den = e;
#pragma unroll
      for (int off = 16; off >= 1; off >>= 1) den += __shfl_xor(den, off);
      c = e / den;
    }
#pragma unroll
    for (int k = 0; k < 16; ++k) sp[k] = fmaf(c, f[k], sp[k]);
  }

  __shared__ float red[8][32][33];
  {
    float* rp = &red[wv][j][ih * 16];
#pragma unroll
    for (int k = 0; k < 4; ++k) *(float4*)(rp + k * 4) = *(float4*)&sp[k * 4];
  }
  __syncthreads();
  const int o = tid * 2;  // 0..1022: (j = o>>5, d = o&31)
  const int jj = o >> 5;
  const int dd = o & 31;
  float2 v{0.f, 0.f};
#pragma unroll
  for (int w = 0; w < 8; ++w) {
    v.x += red[w][jj][dd];
    v.y += red[w][jj][dd + 1];
  }
  *(float2*)(part + ((size_t)ic * 64 + b) * 1024 + o) = v;
}

// ---------------- Q: fold 16 partials + squash (wide) ----------------
// 128 blocks x 512 thr: thread = (bj = t>>5, d = t&31). s2 via 32-lane reduce.
// MODE 0: acc = squash(s); MODE 1: acc += squash(s); MODE 2: out = squash(s)
template <int MODE>
__global__ __launch_bounds__(512) void k_squash(const float* __restrict__ part,
                                                float* __restrict__ accg,
                                                float* __restrict__ outg) {
  const int t = blockIdx.x * 512 + threadIdx.x;  // 0..65535 = (b*32+j)*32 + d
  float v = 0.f;
#pragma unroll
  for (int ic = 0; ic < 16; ++ic) v += part[(size_t)ic * 65536 + t];
  float p2 = v * v;
#pragma unroll
  for (int off = 16; off >= 1; off >>= 1) p2 += __shfl_xor(p2, off);
  const float scale = p2 / ((1.f + p2) * sqrtf(p2 + 1e-7f));
  if (MODE == 0) {
    accg[t] = scale * v;
  } else if (MODE == 1) {
    accg[t] += scale * v;
  } else {
    outg[t] = scale * v;
  }
}

extern "C" void kernel_launch(void* const* d_in, const int* in_sizes, int n_in,
                              void* d_out, int out_size, void* d_ws, size_t ws_size,
                              hipStream_t stream) {
  const float* x = (const float*)d_in[0];  // [64,2048,16]
  const float* W = (const float*)d_in[1];  // [32,2048,32,16]
  float* out = (float*)d_out;              // [64,32,32]
  uint32_t* uh = (uint32_t*)d_ws;
  float* part = (float*)((char*)d_ws + (size_t)UH_BYTES);
  float* acc = part + 16 * 64 * 1024;

  k_uhat<<<512, 512, 0, stream>>>(x, W, uh);
  k_route<1><<<1024, 512, 0, stream>>>(uh, acc, part);  // iter 0: uniform c
  k_squash<0><<<128, 512, 0, stream>>>(part, acc, out); // acc = out0
  k_route<0><<<1024, 512, 0, stream>>>(uh, acc, part);  // iter 1
  k_squash<1><<<128, 512, 0, stream>>>(part, acc, out); // acc = out0+out1
  k_route<0><<<1024, 512, 0, stream>>>(uh, acc, part);  // iter 2
  k_squash<2><<<128, 512, 0, stream>>>(part, acc, out); // final -> d_out
}